// Round 5
// baseline (69.757 us; speedup 1.0000x reference)
//
#include <hip/hip_runtime.h>

// Problem constants (fixed by the reference setup)
#define Bc   2
#define Cc   256
#define Hc   80
#define Wc   160
#define Gc   4
#define Sc   9
#define GCc  64              // channels per group
#define HWc  (Hc * Wc)
#define H2c  (Hc / 2)        // 40 row-pair tiles
#define WTc  (Wc / 32)       // 5 col tiles of 32
#define NW   4               // waves per block
#define CPW  16              // channels per wave
#define NPAIR 8              // processed as 8 channel-PAIRS

// Interleaved pair tile: [20 rows][64 cols][2 chan] f32 = 10KB/wave (single buf)
#define RROWS  20
#define NCOLSP 64
#define TWORDS (RROWS * NCOLSP * 2)   // 2560 floats per wave

typedef float f4 __attribute__((ext_vector_type(4)));
typedef __attribute__((address_space(3))) float* lfp;

// R4 was LDS-read-pipe bound (18x ds_read2_b32 + random-gather conflicts per
// channel). This version stages channel PAIRS interleaved so one ds_read2_b64
// covers 2 channels x 2 x-corners; row t+1 is always imm offset +64 pairs.
// 2 LDS read instrs per sample per 2 channels (was 8) at 2x bytes/instr.
__global__ __launch_bounds__(256, 3)
void aoc_corr_kernel(const float* __restrict__ left,
                     const float* __restrict__ right,
                     const float* __restrict__ flow,
                     const float* __restrict__ extra,
                     float* __restrict__ out)
{
    __shared__ float tile[NW][TWORDS];   // 40960 B; reduce buf aliased later

    int bid = blockIdx.x;
    int wt = bid % WTc; bid /= WTc;
    int h2 = bid % H2c; bid /= H2c;
    int g  = bid % Gc;  bid /= Gc;
    int b  = bid;

    const int tid  = threadIdx.x;
    const int wid  = tid >> 6;
    const int lane = tid & 63;
    const int r    = lane >> 5;
    const int col  = lane & 31;
    const int h    = h2 * 2 + r;
    const int w    = wt * 32 + col;
    const int pix  = h * Wc + w;

    const float* flowb = flow + (size_t)b * 2 * HWc;
    const float bx = (float)w + flowb[pix];
    const float by = (float)h + flowb[HWc + pix];

    int   xb9[Sc], y09[Sc], y19[Sc];
    float w00[Sc], w01[Sc], w10[Sc], w11[Sc];
    int minX = 1 << 30, maxX = -(1 << 30), minY = 1 << 30, maxY = -(1 << 30);

    const float* exb = extra + (size_t)b * (2 * Sc) * HWc + pix;
#pragma unroll
    for (int s = 0; s < Sc; ++s) {
        const float ex = exb[(size_t)(2 * s) * HWc];
        const float ey = exb[(size_t)(2 * s + 1) * HWc];
        const float x = bx + (float)(s - 4) + ex;   // window: x offset s-4, y 0
        const float y = by + ey;

        const float x0f = floorf(x);
        const float y0f = floorf(y);
        const float fx = x - x0f;
        const float fy = y - y0f;
        const int x0 = (int)x0f;
        const int y0 = (int)y0f;
        const int y1 = y0 + 1;

        const int xb = min(max(x0, 0), Wc - 2);
        const float cA = (x0 == xb) ? (1.0f - fx) : ((x0 == -1)     ? fx          : 0.0f);
        const float cB = (x0 == xb) ? fx          : ((x0 == Wc - 1) ? (1.0f - fx) : 0.0f);
        const float r0 = (y0 >= 0 && y0 < Hc) ? (1.0f - fy) : 0.0f;
        const float r1 = (y1 >= 0 && y1 < Hc) ? fy          : 0.0f;
        const int yc0 = min(max(y0, 0), Hc - 1);
        const int yc1 = min(max(y1, 0), Hc - 1);

        w00[s] = cA * r0;  w01[s] = cB * r0;
        w10[s] = cA * r1;  w11[s] = cB * r1;
        xb9[s] = xb;  y09[s] = yc0;  y19[s] = yc1;

        minX = min(minX, xb);
        maxX = max(maxX, xb);
        minY = min(minY, min(yc0, yc1));
        maxY = max(maxY, max(yc0, yc1));
    }

    // Wave-wide min/max of the clamped footprint (identical across waves)
#pragma unroll
    for (int k = 1; k < 64; k <<= 1) {
        minX = min(minX, __shfl_xor(minX, k));
        maxX = max(maxX, __shfl_xor(maxX, k));
        minY = min(minY, __shfl_xor(minY, k));
        maxY = max(maxY, __shfl_xor(maxY, k));
    }
    // 16B-aligned 64-wide column window always covering [xb, xb+1]
    const int minX2 = min(minX, Wc - NCOLSP) & ~3;
    const bool valid = (maxY - minY + 1 <= RROWS) && (maxX + 1 - minX2 <= 63);

    const float* Rb = right + ((size_t)b * Cc + (size_t)(g * GCc + wid * CPW)) * HWc;
    const float* Lb = left  + ((size_t)b * Cc + (size_t)(g * GCc + wid * CPW)) * HWc + pix;

    float acc[Sc];
#pragma unroll
    for (int s = 0; s < Sc; ++s) acc[s] = 0.0f;

    if (valid) {
        // Per-sample: base row t so reads are rows (t, t+1); weights folded
        // onto the two slots (degenerate clamp cases have zero weights on the
        // irrelevant slot; verified for top/bottom edges incl. minY==79).
        float W0a[Sc], W0b[Sc], W1a[Sc], W1b[Sc];
        unsigned va[Sc];
#pragma unroll
        for (int s = 0; s < Sc; ++s) {
            int t = min(y09[s], Hc - 2);
            t = max(t, minY);
            const int sA = y09[s] - t;      // 0 or 1
            const int sB = y19[s] - t;      // 0 or 1, >= sA
            W0a[s] = (sA ? 0.0f : w00[s]) + (sB ? 0.0f : w10[s]);
            W0b[s] = (sA ? 0.0f : w01[s]) + (sB ? 0.0f : w11[s]);
            W1a[s] = (sA ? w00[s] : 0.0f) + (sB ? w10[s] : 0.0f);
            W1b[s] = (sA ? w01[s] : 0.0f) + (sB ? w11[s] : 0.0f);
            const int dx = xb9[s] - minX2;
            va[s] = (unsigned)(size_t)(lfp)&tile[wid][((t - minY) * NCOLSP + dx) * 2];
        }

        // Staging geometry: one global_load_dwordx4 per (4-row group x chan);
        // lane covers (row = minY+4k+(lane>>4) clamped, 16B col segment).
        const int ls  = lane >> 4;
        const int seg = lane & 15;
        int rowEl[5];
#pragma unroll
        for (int k = 0; k < 5; ++k)
            rowEl[k] = min(minY + 4 * k + ls, Hc - 1) * Wc + minX2 + seg * 4;

        // Prologue: load pair 0
        f4 c0[5], c1[5];
#pragma unroll
        for (int k = 0; k < 5; ++k) {
            c0[k] = *(const f4*)(Rb + rowEl[k]);
            c1[k] = *(const f4*)(Rb + HWc + rowEl[k]);
        }
        float lv0 = Lb[0], lv1 = Lb[HWc];

        for (int p = 0; p < NPAIR; ++p) {
            // Write pair p interleaved: [row][col][2chan]
#pragma unroll
            for (int k = 0; k < 5; ++k) {
                float* q = &tile[wid][(4 * k + ls) * (NCOLSP * 2) + seg * 8];
                f4 a = c0[k], bb = c1[k];
                f4 q0 = {a[0], bb[0], a[1], bb[1]};
                f4 q1 = {a[2], bb[2], a[3], bb[3]};
                *(f4*)q = q0;
                *(f4*)(q + 4) = q1;
            }
            // Prefetch pair p+1 (in flight under this pair's compute)
            if (p + 1 < NPAIR) {
                const float* Rn = Rb + (size_t)(2 * (p + 1)) * HWc;
#pragma unroll
                for (int k = 0; k < 5; ++k) {
                    c0[k] = *(const f4*)(Rn + rowEl[k]);
                    c1[k] = *(const f4*)(Rn + HWc + rowEl[k]);
                }
            }
            float nl0 = 0.0f, nl1 = 0.0f;
            if (p + 1 < NPAIR) {
                nl0 = Lb[(size_t)(2 * p + 2) * HWc];
                nl1 = Lb[(size_t)(2 * p + 3) * HWc];
            }

            // Gather + FMA, 2 samples per batch. One ds_read2_b64 = 2 chans x
            // 2 x-corners; second = row t+1 via imm offset (+64 pairs).
#pragma unroll
            for (int sb = 0; sb < Sc; sb += 2) {
                f4 ra0, rb0, ra1, rb1;
                asm volatile(
                    "ds_read2_b64 %0, %2 offset0:0 offset1:1\n\t"
                    "ds_read2_b64 %1, %2 offset0:64 offset1:65"
                    : "=v"(ra0), "=v"(rb0) : "v"(va[sb]) : "memory");
                if (sb + 1 < Sc)
                    asm volatile(
                        "ds_read2_b64 %0, %2 offset0:0 offset1:1\n\t"
                        "ds_read2_b64 %1, %2 offset0:64 offset1:65"
                        : "=v"(ra1), "=v"(rb1) : "v"(va[sb + 1]) : "memory");
                asm volatile("s_waitcnt lgkmcnt(0)" ::: "memory");
                __builtin_amdgcn_sched_barrier(0);

                {
                    const float s0 = W0a[sb] * ra0[0] + W0b[sb] * ra0[2]
                                   + W1a[sb] * rb0[0] + W1b[sb] * rb0[2];
                    const float s1 = W0a[sb] * ra0[1] + W0b[sb] * ra0[3]
                                   + W1a[sb] * rb0[1] + W1b[sb] * rb0[3];
                    acc[sb] += lv0 * s0 + lv1 * s1;
                }
                if (sb + 1 < Sc) {
                    const int s = sb + 1;
                    const float s0 = W0a[s] * ra1[0] + W0b[s] * ra1[2]
                                   + W1a[s] * rb1[0] + W1b[s] * rb1[2];
                    const float s1 = W0a[s] * ra1[1] + W0b[s] * ra1[3]
                                   + W1a[s] * rb1[1] + W1b[s] * rb1[3];
                    acc[s] += lv0 * s0 + lv1 * s1;
                }
            }
            lv0 = nl0; lv1 = nl1;
        }
    } else {
        // Fallback: direct global gathers (proven path; footprint outliers)
        int offA[Sc], offB[Sc];
#pragma unroll
        for (int s = 0; s < Sc; ++s) {
            offA[s] = y09[s] * Wc + xb9[s];
            offB[s] = y19[s] * Wc + xb9[s];
        }
        for (int c = 0; c < CPW; ++c) {
            const float lv = Lb[(size_t)c * HWc];
            const float* Rc = Rb + (size_t)c * HWc;
#pragma unroll
            for (int s = 0; s < Sc; ++s) {
                const float vA0 = Rc[offA[s]];
                const float vA1 = Rc[offA[s] + 1];
                const float vB0 = Rc[offB[s]];
                const float vB1 = Rc[offB[s] + 1];
                acc[s] += lv * (w00[s] * vA0 + w01[s] * vA1 +
                                w10[s] * vB0 + w11[s] * vB1);
            }
        }
    }

    // 4-way cross-wave reduction; reduce buffer aliases the dead tile memory.
    float* red = &tile[0][0];   // (NW-1) * Sc * 64 = 1728 floats
    __syncthreads();
    if (wid != 0) {
#pragma unroll
        for (int s = 0; s < Sc; ++s)
            red[((wid - 1) * Sc + s) * 64 + lane] = acc[s];
    }
    __syncthreads();
    if (wid == 0) {
        const float inv = 1.0f / (float)GCc;
        float* ob = out + ((size_t)b * Gc + g) * Sc * HWc + pix;
#pragma unroll
        for (int s = 0; s < Sc; ++s) {
            float v = acc[s];
#pragma unroll
            for (int ww = 1; ww < NW; ++ww)
                v += red[((ww - 1) * Sc + s) * 64 + lane];
            ob[(size_t)s * HWc] = v * inv;
        }
    }
}

extern "C" void kernel_launch(void* const* d_in, const int* in_sizes, int n_in,
                              void* d_out, int out_size, void* d_ws, size_t ws_size,
                              hipStream_t stream) {
    const float* left  = (const float*)d_in[0];
    const float* right = (const float*)d_in[1];
    const float* flow  = (const float*)d_in[2];
    const float* extra = (const float*)d_in[3];
    float* out = (float*)d_out;

    const int nblocks = Bc * Gc * H2c * WTc;  // 2*4*40*5 = 1600
    aoc_corr_kernel<<<nblocks, NW * 64, 0, stream>>>(left, right, flow, extra, out);
}

// Round 7
// 57.056 us; speedup vs baseline: 1.2226x; 1.2226x over previous
//
#include <hip/hip_runtime.h>

// Problem constants (fixed by the reference setup)
#define Bc   2
#define Cc   256
#define Hc   80
#define Wc   160
#define Gc   4
#define Sc   9
#define GCc  64              // channels per group
#define HWc  (Hc * Wc)
#define H2c  (Hc / 2)        // 40 row-pair tiles
#define WTc  (Wc / 32)       // 5 col tiles of 32
#define NW   4               // waves per block
#define CPW  16              // channels per wave

// fp16 vertical-pair tile: dword (t,x) = fp16x2(v(minY+t,x), v(minY+t+1,x)).
// PROWS pair-rows (21 underlying rows), 64 cols + 2 pad (stride even so
// ds_write_b64 stays 8B-aligned; bank = (66t+dx)%32, full 32-bank spread).
// DOUBLE-BUFFERED (R6 post-mortem): single buffer + TBAA no-alias between
// vector stores and scalar loads let the compiler reorder next-channel
// ds_writes past pending ds_reads -> timing-dependent corruption.
#define PROWS   20
#define TSTRIDE 66
#define TDW     (PROWS * TSTRIDE)    // 1320 dwords = 5280 B per buffer

typedef float f4 __attribute__((ext_vector_type(4)));
typedef _Float16 h2 __attribute__((ext_vector_type(2)));
typedef unsigned u2 __attribute__((ext_vector_type(2)));

static __device__ __forceinline__ unsigned pk(float a, float b) {
    return __builtin_bit_cast(unsigned, __builtin_amdgcn_cvt_pkrtz(a, b));
}
static __device__ __forceinline__ float dot2(unsigned w, unsigned v, float c) {
#if __has_builtin(__builtin_amdgcn_fdot2)
    return __builtin_amdgcn_fdot2(__builtin_bit_cast(h2, w),
                                  __builtin_bit_cast(h2, v), c, false);
#else
    h2 hw = __builtin_bit_cast(h2, w), hv = __builtin_bit_cast(h2, v);
    return c + (float)hw[0] * (float)hv[0] + (float)hw[1] * (float)hv[1];
#endif
}

// Compiler-only memory fence: pins LDS read/write program order against
// TBAA-driven reordering (zero instructions emitted).
#define CFENCE() asm volatile("" ::: "memory")

__global__ __launch_bounds__(256, 3)
void aoc_corr_kernel(const float* __restrict__ left,
                     const float* __restrict__ right,
                     const float* __restrict__ flow,
                     const float* __restrict__ extra,
                     float* __restrict__ out)
{
    __shared__ unsigned tile[NW][2][TDW];   // 42240 B; reduce buf aliased later

    int bid = blockIdx.x;
    int wt = bid % WTc; bid /= WTc;
    int h2i = bid % H2c; bid /= H2c;
    int g  = bid % Gc;  bid /= Gc;
    int b  = bid;

    const int tid  = threadIdx.x;
    const int wid  = tid >> 6;
    const int lane = tid & 63;
    const int r    = lane >> 5;
    const int col  = lane & 31;
    const int h    = h2i * 2 + r;
    const int w    = wt * 32 + col;
    const int pix  = h * Wc + w;

    const float* flowb = flow + (size_t)b * 2 * HWc;
    const float bx = (float)w + flowb[pix];
    const float by = (float)h + flowb[HWc + pix];

    int   xb9[Sc], y09[Sc], y19[Sc];
    float w00[Sc], w01[Sc], w10[Sc], w11[Sc];
    int minX = 1 << 30, maxX = -(1 << 30), minY = 1 << 30, maxY = -(1 << 30);

    const float* exb = extra + (size_t)b * (2 * Sc) * HWc + pix;
#pragma unroll
    for (int s = 0; s < Sc; ++s) {
        const float ex = exb[(size_t)(2 * s) * HWc];
        const float ey = exb[(size_t)(2 * s + 1) * HWc];
        const float x = bx + (float)(s - 4) + ex;   // window: x offset s-4, y 0
        const float y = by + ey;

        const float x0f = floorf(x);
        const float y0f = floorf(y);
        const float fx = x - x0f;
        const float fy = y - y0f;
        const int x0 = (int)x0f;
        const int y0 = (int)y0f;
        const int y1 = y0 + 1;

        const int xb = min(max(x0, 0), Wc - 2);
        const float cA = (x0 == xb) ? (1.0f - fx) : ((x0 == -1)     ? fx          : 0.0f);
        const float cB = (x0 == xb) ? fx          : ((x0 == Wc - 1) ? (1.0f - fx) : 0.0f);
        const float r0 = (y0 >= 0 && y0 < Hc) ? (1.0f - fy) : 0.0f;
        const float r1 = (y1 >= 0 && y1 < Hc) ? fy          : 0.0f;
        const int yc0 = min(max(y0, 0), Hc - 1);
        const int yc1 = min(max(y1, 0), Hc - 1);

        w00[s] = cA * r0;  w01[s] = cB * r0;
        w10[s] = cA * r1;  w11[s] = cB * r1;
        xb9[s] = xb;  y09[s] = yc0;  y19[s] = yc1;

        minX = min(minX, xb);
        maxX = max(maxX, xb);
        minY = min(minY, min(yc0, yc1));
        maxY = max(maxY, max(yc0, yc1));
    }

    // Wave-wide min/max of the clamped footprint (identical across waves)
#pragma unroll
    for (int k = 1; k < 64; k <<= 1) {
        minX = min(minX, __shfl_xor(minX, k));
        maxX = max(maxX, __shfl_xor(maxX, k));
        minY = min(minY, __shfl_xor(minY, k));
        maxY = max(maxY, __shfl_xor(maxY, k));
    }
    // 16B-aligned 64-wide column window covering [xb, xb+1] for all lanes
    const int minX2 = min(minX, Wc - 64) & ~3;
    const bool valid = (maxY - minY + 1 <= PROWS) && (maxX - minX2 <= 62);

    const float* Rb = right + ((size_t)b * Cc + (size_t)(g * GCc + wid * CPW)) * HWc;
    const float* Lb = left  + ((size_t)b * Cc + (size_t)(g * GCc + wid * CPW)) * HWc + pix;

    float acc[Sc];
#pragma unroll
    for (int s = 0; s < Sc; ++s) acc[s] = 0.0f;

    if (valid) {
        // Per-sample: pair-row t holds rows (y09, y09+1); fold weights onto
        // the two fp16 slots by ROW IDENTITY (handles all clamp cases:
        // y0==-1 -> y09==y19 -> slot0 gets w00+w10; y0==79 -> w10=w11=0).
        unsigned wA[Sc], wB[Sc];
        int idx[Sc];
#pragma unroll
        for (int s = 0; s < Sc; ++s) {
            const int t  = y09[s] - minY;          // 0..PROWS-1 under valid
            const int sB = y19[s] - y09[s];        // 0 or 1
            const float A0 = w00[s] + (sB ? 0.0f : w10[s]);
            const float A1 = sB ? w10[s] : 0.0f;
            const float B0 = w01[s] + (sB ? 0.0f : w11[s]);
            const float B1 = sB ? w11[s] : 0.0f;
            wA[s] = pk(A0, A1);
            wB[s] = pk(B0, B1);
            idx[s] = t * TSTRIDE + (xb9[s] - minX2);
        }

        // Staging geometry: lane-group ls covers underlying rows
        // [5*ls, 5*ls+5] (6 rows, +1 overlap for vertical pairing),
        // 16B col segment seg. 21 underlying rows -> 20 pair-rows.
        const int ls  = lane >> 4;
        const int seg = lane & 15;
        int rowEl[6];
#pragma unroll
        for (int k = 0; k < 6; ++k)
            rowEl[k] = min(minY + 5 * ls + k, Hc - 1) * Wc + minX2 + seg * 4;

        // Prologue: load channel 0 rows into regs
        f4 rv[6];
#pragma unroll
        for (int k = 0; k < 6; ++k) rv[k] = *(const f4*)(Rb + rowEl[k]);
        float lv = Lb[0];

#pragma unroll 1
        for (int c = 0; c < CPW; ++c) {
            unsigned* tw = tile[wid][c & 1];
            // Convert + write channel c's vertical fp16 pairs into buffer
            // (c&1). Reads of this buffer happened 2 iterations ago and were
            // consumed (compiler-inserted lgkmcnt drain) -> no WAR hazard.
            CFENCE();
#pragma unroll
            for (int j = 0; j < 5; ++j) {
                unsigned* q = tw + (5 * ls + j) * TSTRIDE + seg * 4;
                u2 lo = { pk(rv[j][0], rv[j + 1][0]), pk(rv[j][1], rv[j + 1][1]) };
                u2 hi = { pk(rv[j][2], rv[j + 1][2]), pk(rv[j][3], rv[j + 1][3]) };
                *(u2*)q       = lo;    // ds_write_b64 (addr even-dword)
                *(u2*)(q + 2) = hi;
            }
            CFENCE();
            // Prefetch channel c+1 (stays in flight under compute of c)
            float lvn = 0.0f;
            if (c + 1 < CPW) {
                const float* Rn = Rb + (size_t)(c + 1) * HWc;
#pragma unroll
                for (int k = 0; k < 6; ++k) rv[k] = *(const f4*)(Rn + rowEl[k]);
                lvn = Lb[(size_t)(c + 1) * HWc];
            }
            // Compute: per sample ONE ds_read2_b32 (dwords idx, idx+1) =
            // all 4 bilinear corners; 2x dot2 + 1 fma.
#pragma unroll
            for (int s = 0; s < Sc; ++s) {
                const unsigned d0 = tw[idx[s]];
                const unsigned d1 = tw[idx[s] + 1];
                float sd = dot2(wA[s], d0, 0.0f);
                sd = dot2(wB[s], d1, sd);
                acc[s] = fmaf(lv, sd, acc[s]);
            }
            lv = lvn;
        }
    } else {
        // Fallback: direct global gathers, full f32 (footprint outliers)
        int offA[Sc], offB[Sc];
#pragma unroll
        for (int s = 0; s < Sc; ++s) {
            offA[s] = y09[s] * Wc + xb9[s];
            offB[s] = y19[s] * Wc + xb9[s];
        }
        for (int c = 0; c < CPW; ++c) {
            const float lv = Lb[(size_t)c * HWc];
            const float* Rc = Rb + (size_t)c * HWc;
#pragma unroll
            for (int s = 0; s < Sc; ++s) {
                const float vA0 = Rc[offA[s]];
                const float vA1 = Rc[offA[s] + 1];
                const float vB0 = Rc[offB[s]];
                const float vB1 = Rc[offB[s] + 1];
                acc[s] += lv * (w00[s] * vA0 + w01[s] * vA1 +
                                w10[s] * vB0 + w11[s] * vB1);
            }
        }
    }

    // 4-way cross-wave reduction; reduce buffer aliases the dead tile memory.
    float* red = (float*)&tile[0][0][0];   // 3*9*64*4 = 6912 B <= 42240 B
    __syncthreads();
    if (wid != 0) {
#pragma unroll
        for (int s = 0; s < Sc; ++s)
            red[((wid - 1) * Sc + s) * 64 + lane] = acc[s];
    }
    __syncthreads();
    if (wid == 0) {
        const float inv = 1.0f / (float)GCc;
        float* ob = out + ((size_t)b * Gc + g) * Sc * HWc + pix;
#pragma unroll
        for (int s = 0; s < Sc; ++s) {
            float v = acc[s];
#pragma unroll
            for (int ww = 1; ww < NW; ++ww)
                v += red[((ww - 1) * Sc + s) * 64 + lane];
            ob[(size_t)s * HWc] = v * inv;
        }
    }
}

extern "C" void kernel_launch(void* const* d_in, const int* in_sizes, int n_in,
                              void* d_out, int out_size, void* d_ws, size_t ws_size,
                              hipStream_t stream) {
    const float* left  = (const float*)d_in[0];
    const float* right = (const float*)d_in[1];
    const float* flow  = (const float*)d_in[2];
    const float* extra = (const float*)d_in[3];
    float* out = (float*)d_out;

    const int nblocks = Bc * Gc * H2c * WTc;  // 2*4*40*5 = 1600
    aoc_corr_kernel<<<nblocks, NW * 64, 0, stream>>>(left, right, flow, extra, out);
}